// Round 1
// baseline (288.487 us; speedup 1.0000x reference)
//
#include <hip/hip_runtime.h>
#include <hip/hip_bf16.h>
#include <stdint.h>

typedef __bf16 bf16x8 __attribute__((ext_vector_type(8)));
typedef float  f32x4  __attribute__((ext_vector_type(4)));

#define D_MODEL 512
#define N_HEAD  8
#define HD      64
#define NB      8
#define L_      1024
#define REL_ROWS 2064   // 2048 + padding rows (zero) for window over-read

__device__ __forceinline__ unsigned short f2bf(float f) {
  unsigned int u = __builtin_bit_cast(unsigned int, f);
  u += 0x7FFFu + ((u >> 16) & 1u);
  return (unsigned short)(u >> 16);
}
__device__ __forceinline__ float bf2f(unsigned short h) {
  unsigned int u = ((unsigned int)h) << 16;
  return __builtin_bit_cast(float, u);
}

// ---------------- rel = pos_embed(2L, 64) @ w_kr, stored bf16, zero-padded rows ----------------
__global__ __launch_bounds__(256) void k_prep_rel(const float* __restrict__ w_kr,
                                                  unsigned short* __restrict__ rel) {
  int tid = blockIdx.x * 256 + threadIdx.x;
  int j = tid >> 6, d = tid & 63;
  if (j >= REL_ROWS) return;
  float acc = 0.f;
  if (j < 2 * L_) {
    float pos = (float)j - (float)L_;
    const float kInv = -9.210340371976184f / 31.0f;  // -ln(10000)/(half-1)
    for (int i = 0; i < 32; ++i) {
      float fr  = expf((float)i * kInv);
      float ang = pos * fr;
      acc += sinf(ang) * w_kr[i * HD + d] + cosf(ang) * w_kr[(i + 32) * HD + d];
    }
  }
  rel[j * HD + d] = f2bf(acc);
}

// ---------------- x (f32) -> bf16 ----------------
__global__ __launch_bounds__(256) void k_cvt_x(const float* __restrict__ x,
                                               unsigned short* __restrict__ xbf) {
  int t = blockIdx.x * 256 + threadIdx.x;
  const float4* p = reinterpret_cast<const float4*>(x) + (size_t)t * 2;
  float4 a = p[0], b = p[1];
  ushort4 o0 = { f2bf(a.x), f2bf(a.y), f2bf(a.z), f2bf(a.w) };
  ushort4 o1 = { f2bf(b.x), f2bf(b.y), f2bf(b.z), f2bf(b.w) };
  ushort4* q = reinterpret_cast<ushort4*>(xbf) + (size_t)t * 2;
  q[0] = o0; q[1] = o1;
}

// ---------------- W_qkv [512,1536] f32 -> Wt [1536,512] bf16 (transpose via LDS) ----------------
__global__ __launch_bounds__(256) void k_cvt_wt(const float* __restrict__ W,
                                                unsigned short* __restrict__ Wt) {
  __shared__ float tile[32][33];
  int kb = blockIdx.x;   // 16
  int nb = blockIdx.y;   // 48
  int t = threadIdx.x;
  int r = t >> 3, c4 = (t & 7) * 4;
  float4 v = *reinterpret_cast<const float4*>(W + (size_t)(kb * 32 + r) * 1536 + nb * 32 + c4);
  tile[r][c4 + 0] = v.x; tile[r][c4 + 1] = v.y; tile[r][c4 + 2] = v.z; tile[r][c4 + 3] = v.w;
  __syncthreads();
  int a = t >> 3, b4 = (t & 7) * 4;
  ushort4 o = { f2bf(tile[b4 + 0][a]), f2bf(tile[b4 + 1][a]),
                f2bf(tile[b4 + 2][a]), f2bf(tile[b4 + 3][a]) };
  *reinterpret_cast<ushort4*>(Wt + (size_t)(nb * 32 + a) * 512 + kb * 32 + b4) = o;
}

// ---------------- QKV = Xbf @ Wt^T  -> [8192, 1536] bf16 ----------------
__global__ __launch_bounds__(256) void k_gemm_qkv(const unsigned short* __restrict__ Xbf,
                                                  const unsigned short* __restrict__ Wt,
                                                  unsigned short* __restrict__ QKV) {
  int m0 = blockIdx.x * 128;
  int n0 = blockIdx.y * 128;
  int w = threadIdx.x >> 6, lane = threadIdx.x & 63;
  int lr = lane & 15, g = lane >> 4;
  int wm = (w >> 1) * 64, wn = (w & 1) * 64;
  f32x4 acc[4][4];
  for (int i = 0; i < 4; ++i) for (int j = 0; j < 4; ++j) acc[i][j] = (f32x4){0.f, 0.f, 0.f, 0.f};
  const unsigned short* Ar[4]; const unsigned short* Br[4];
  for (int mt = 0; mt < 4; ++mt) Ar[mt] = Xbf + (size_t)(m0 + wm + mt * 16 + lr) * 512;
  for (int nt = 0; nt < 4; ++nt) Br[nt] = Wt  + (size_t)(n0 + wn + nt * 16 + lr) * 512;
#pragma unroll 2
  for (int ks = 0; ks < 16; ++ks) {
    int off = ks * 32 + g * 8;
    bf16x8 a[4], b[4];
    for (int mt = 0; mt < 4; ++mt)
      a[mt] = __builtin_bit_cast(bf16x8, *reinterpret_cast<const uint4*>(Ar[mt] + off));
    for (int nt = 0; nt < 4; ++nt)
      b[nt] = __builtin_bit_cast(bf16x8, *reinterpret_cast<const uint4*>(Br[nt] + off));
    for (int mt = 0; mt < 4; ++mt)
      for (int nt = 0; nt < 4; ++nt)
        acc[mt][nt] = __builtin_amdgcn_mfma_f32_16x16x32_bf16(a[mt], b[nt], acc[mt][nt], 0, 0, 0);
  }
  for (int mt = 0; mt < 4; ++mt)
    for (int nt = 0; nt < 4; ++nt)
      for (int r = 0; r < 4; ++r) {
        int m = m0 + wm + mt * 16 + g * 4 + r;
        int n = n0 + wn + nt * 16 + lr;
        QKV[(size_t)m * 1536 + n] = f2bf(acc[mt][nt][r]);
      }
}

// ---------------- Vt[b,h,d,l] <- QKV v-columns (transpose via LDS) ----------------
__global__ __launch_bounds__(256) void k_vtrans(const unsigned short* __restrict__ QKV,
                                                unsigned short* __restrict__ Vt) {
  __shared__ unsigned short tile[64][72];
  int bh = blockIdx.x;   // 64
  int lt = blockIdx.y;   // 16
  int b = bh >> 3, h = bh & 7;
  int t = threadIdx.x;
  int i = t >> 2, d0 = (t & 3) * 16;
  const uint4* src = reinterpret_cast<const uint4*>(
      QKV + (size_t)(b * L_ + lt * 64 + i) * 1536 + 2 * D_MODEL + h * HD + d0);
  uint4 v0 = src[0], v1 = src[1];
  *reinterpret_cast<uint4*>(&tile[i][d0])     = v0;
  *reinterpret_cast<uint4*>(&tile[i][d0 + 8]) = v1;
  __syncthreads();
  int dd = t >> 2, c0 = (t & 3) * 16;
  unsigned short o[16];
  for (int j = 0; j < 16; ++j) o[j] = tile[c0 + j][dd];
  uint4* dst = reinterpret_cast<uint4*>(Vt + (size_t)(bh * HD + dd) * L_ + lt * 64 + c0);
  dst[0] = *reinterpret_cast<const uint4*>(&o[0]);
  dst[1] = *reinterpret_cast<const uint4*>(&o[8]);
}

// ---------------- fused relative attention ----------------
#define SCALE 0.125f

__global__ __launch_bounds__(256) void k_attn(const unsigned short* __restrict__ QKV,
                                              const unsigned short* __restrict__ Vt,
                                              const unsigned short* __restrict__ rel,
                                              const int* __restrict__ mask,
                                              const float* __restrict__ rrb,
                                              const float* __restrict__ rwb,
                                              float* __restrict__ out) {
  __shared__ int maskS[L_];
  __shared__ float winS[4][16 * 83];
  __shared__ unsigned short pS[4][16 * 72];
  int blk = blockIdx.x;
  int bh = blk >> 4, qt = blk & 15;
  int b = bh >> 3, h = bh & 7;
  int w = threadIdx.x >> 6, lane = threadIdx.x & 63;
  int lr = lane & 15, g = lane >> 4;
  int qw0 = qt * 64 + w * 16;

  for (int idx = threadIdx.x; idx < L_; idx += 256) maskS[idx] = mask[b * L_ + idx];
  __syncthreads();

  // q fragments, with r_r_bias (AC path) and r_w_bias (rel path) folded in
  bf16x8 qrr[2], qrw[2];
  {
    const unsigned short* qrow = QKV + (size_t)(b * L_ + qw0 + lr) * 1536 + h * HD;
    for (int ks = 0; ks < 2; ++ks) {
      uint4 raw = *reinterpret_cast<const uint4*>(qrow + ks * 32 + g * 8);
      unsigned short* rb = reinterpret_cast<unsigned short*>(&raw);
      unsigned short arr_rr[8], arr_rw[8];
      for (int j = 0; j < 8; ++j) {
        int d = ks * 32 + g * 8 + j;
        float f = bf2f(rb[j]);
        arr_rr[j] = f2bf(f + rrb[h * HD + d]);
        arr_rw[j] = f2bf(f + rwb[h * HD + d]);
      }
      qrr[ks] = __builtin_bit_cast(bf16x8, *reinterpret_cast<uint4*>(arr_rr));
      qrw[ks] = __builtin_bit_cast(bf16x8, *reinterpret_cast<uint4*>(arr_rw));
    }
  }

  float m_r[4], l_r[4];
  f32x4 accO[4];
  for (int r = 0; r < 4; ++r) { m_r[r] = -INFINITY; l_r[r] = 0.f; }
  for (int nt = 0; nt < 4; ++nt) accO[nt] = (f32x4){0.f, 0.f, 0.f, 0.f};

  float* win = winS[w];
  unsigned short* ps = pS[w];

  for (int k0 = 0; k0 < L_; k0 += 64) {
    // ---- windowed B-term GEMM: (q + r_w_bias) @ rel^T over window width 80 ----
    int jbase = L_ + k0 - qw0 - 15;
    f32x4 bw[5];
    for (int u = 0; u < 5; ++u) bw[u] = (f32x4){0.f, 0.f, 0.f, 0.f};
    for (int u = 0; u < 5; ++u) {
      const unsigned short* rrow = rel + (size_t)(jbase + u * 16 + lr) * HD;
      for (int ks = 0; ks < 2; ++ks) {
        bf16x8 bfr = __builtin_bit_cast(bf16x8, *reinterpret_cast<const uint4*>(rrow + ks * 32 + g * 8));
        bw[u] = __builtin_amdgcn_mfma_f32_16x16x32_bf16(qrw[ks], bfr, bw[u], 0, 0, 0);
      }
    }
    for (int u = 0; u < 5; ++u)
      for (int r = 0; r < 4; ++r)
        win[(g * 4 + r) * 83 + u * 16 + lr] = bw[u][r];

    // ---- AC GEMM: (q + r_r_bias) @ k^T ----
    f32x4 ac[4];
    for (int t = 0; t < 4; ++t) ac[t] = (f32x4){0.f, 0.f, 0.f, 0.f};
    for (int t = 0; t < 4; ++t) {
      const unsigned short* krow = QKV + (size_t)(b * L_ + k0 + t * 16 + lr) * 1536 + D_MODEL + h * HD;
      for (int ks = 0; ks < 2; ++ks) {
        bf16x8 kfr = __builtin_bit_cast(bf16x8, *reinterpret_cast<const uint4*>(krow + ks * 32 + g * 8));
        ac[t] = __builtin_amdgcn_mfma_f32_16x16x32_bf16(qrr[ks], kfr, ac[t], 0, 0, 0);
      }
    }

    // ---- scores (shift-gather) + mask + online softmax ----
    float p[4][4];
    for (int r = 0; r < 4; ++r) {
      int ql = g * 4 + r;
      float rm = -INFINITY;
      for (int t = 0; t < 4; ++t) {
        float sb = win[ql * 83 + t * 16 + lr + 15 - ql];   // BD[q,k] = Bwin[q, k_local + 15 - q_local]
        float s = (ac[t][r] + sb) * SCALE;
        s = maskS[k0 + t * 16 + lr] ? s : 1e-9f;
        p[t][r] = s;
        rm = fmaxf(rm, s);
      }
      rm = fmaxf(rm, __shfl_xor(rm, 1, 16));
      rm = fmaxf(rm, __shfl_xor(rm, 2, 16));
      rm = fmaxf(rm, __shfl_xor(rm, 4, 16));
      rm = fmaxf(rm, __shfl_xor(rm, 8, 16));
      float mnew = fmaxf(m_r[r], rm);
      float alpha = __expf(m_r[r] - mnew);
      float rs = 0.f;
      for (int t = 0; t < 4; ++t) {
        float e = __expf(p[t][r] - mnew);
        p[t][r] = e;
        rs += e;
      }
      rs += __shfl_xor(rs, 1, 16);
      rs += __shfl_xor(rs, 2, 16);
      rs += __shfl_xor(rs, 4, 16);
      rs += __shfl_xor(rs, 8, 16);
      l_r[r] = l_r[r] * alpha + rs;
      m_r[r] = mnew;
      for (int nt = 0; nt < 4; ++nt) accO[nt][r] *= alpha;
    }

    // ---- P -> LDS (bf16), A-fragments, PV MFMA ----
    for (int t = 0; t < 4; ++t)
      for (int r = 0; r < 4; ++r)
        ps[(g * 4 + r) * 72 + t * 16 + lr] = f2bf(p[t][r]);
    bf16x8 pa[2];
    for (int ks = 0; ks < 2; ++ks)
      pa[ks] = __builtin_bit_cast(bf16x8, *reinterpret_cast<const uint4*>(ps + lr * 72 + ks * 32 + g * 8));
    for (int nt = 0; nt < 4; ++nt) {
      const unsigned short* vrow = Vt + (size_t)(bh * HD + nt * 16 + lr) * L_ + k0;
      for (int ks = 0; ks < 2; ++ks) {
        bf16x8 vfr = __builtin_bit_cast(bf16x8, *reinterpret_cast<const uint4*>(vrow + ks * 32 + g * 8));
        accO[nt] = __builtin_amdgcn_mfma_f32_16x16x32_bf16(pa[ks], vfr, accO[nt], 0, 0, 0);
      }
    }
  }

  // ---- epilogue: out[b, q, h*64 + d] = O / l ----
  for (int nt = 0; nt < 4; ++nt)
    for (int r = 0; r < 4; ++r) {
      int q = qw0 + g * 4 + r;
      float val = accO[nt][r] / l_r[r];
      out[(size_t)(b * L_ + q) * D_MODEL + h * HD + nt * 16 + lr] = val;
    }
}

extern "C" void kernel_launch(void* const* d_in, const int* in_sizes, int n_in,
                              void* d_out, int out_size, void* d_ws, size_t ws_size,
                              hipStream_t stream) {
  const float* x    = (const float*)d_in[0];
  const int*   mask = (const int*)d_in[1];
  const float* Wqkv = (const float*)d_in[2];
  const float* rrb  = (const float*)d_in[3];
  const float* rwb  = (const float*)d_in[4];
  const float* wkr  = (const float*)d_in[5];
  float* out = (float*)d_out;

  char* ws = (char*)d_ws;
  size_t off = 0;
  unsigned short* REL = (unsigned short*)(ws + off); off += (size_t)REL_ROWS * HD * 2;   // 0.26 MB
  unsigned short* XBF = (unsigned short*)(ws + off); off += (size_t)8192 * 512 * 2;      // 8 MB
  unsigned short* WT  = (unsigned short*)(ws + off); off += (size_t)1536 * 512 * 2;      // 1.5 MB
  unsigned short* QKV = (unsigned short*)(ws + off); off += (size_t)8192 * 1536 * 2;     // 24 MB
  unsigned short* VT  = (unsigned short*)(ws + off); off += (size_t)64 * 64 * 1024 * 2;  // 8 MB

  hipLaunchKernelGGL(k_prep_rel, dim3(516),    dim3(256), 0, stream, wkr, REL);
  hipLaunchKernelGGL(k_cvt_x,    dim3(2048),   dim3(256), 0, stream, x, XBF);
  hipLaunchKernelGGL(k_cvt_wt,   dim3(16, 48), dim3(256), 0, stream, Wqkv, WT);
  hipLaunchKernelGGL(k_gemm_qkv, dim3(64, 12), dim3(256), 0, stream, XBF, WT, QKV);
  hipLaunchKernelGGL(k_vtrans,   dim3(64, 16), dim3(256), 0, stream, QKV, VT);
  hipLaunchKernelGGL(k_attn,     dim3(1024),   dim3(256), 0, stream, QKV, VT, REL, mask, rrb, rwb, out);
}

// Round 2
// 203.457 us; speedup vs baseline: 1.4179x; 1.4179x over previous
//
#include <hip/hip_runtime.h>
#include <hip/hip_bf16.h>
#include <stdint.h>

typedef __bf16 bf16x8 __attribute__((ext_vector_type(8)));
typedef float  f32x4  __attribute__((ext_vector_type(4)));

#define D_MODEL 512
#define N_HEAD  8
#define HD      64
#define L_      1024
#define SCALE   0.125f

__device__ __forceinline__ unsigned short f2bf(float f) {
  unsigned int u = __builtin_bit_cast(unsigned int, f);
  u += 0x7FFFu + ((u >> 16) & 1u);
  return (unsigned short)(u >> 16);
}
__device__ __forceinline__ float bf2f(unsigned short h) {
  unsigned int u = ((unsigned int)h) << 16;
  return __builtin_bit_cast(float, u);
}

__device__ __forceinline__ void gld_lds16(const void* g, void* l) {
  __builtin_amdgcn_global_load_lds(
      (const __attribute__((address_space(1))) void*)g,
      (__attribute__((address_space(3))) void*)l, 16, 0, 0);
}
__device__ __forceinline__ void gld_lds4(const void* g, void* l) {
  __builtin_amdgcn_global_load_lds(
      (const __attribute__((address_space(1))) void*)g,
      (__attribute__((address_space(3))) void*)l, 4, 0, 0);
}

// ---------------- x (f32) -> bf16 ----------------
__global__ __launch_bounds__(256) void k_cvt_x(const float* __restrict__ x,
                                               unsigned short* __restrict__ xbf) {
  int t = blockIdx.x * 256 + threadIdx.x;
  const float4* p = reinterpret_cast<const float4*>(x) + (size_t)t * 2;
  float4 a = p[0], b = p[1];
  ushort4 o0 = { f2bf(a.x), f2bf(a.y), f2bf(a.z), f2bf(a.w) };
  ushort4 o1 = { f2bf(b.x), f2bf(b.y), f2bf(b.z), f2bf(b.w) };
  ushort4* q = reinterpret_cast<ushort4*>(xbf) + (size_t)t * 2;
  q[0] = o0; q[1] = o1;
}

// ---------------- W_qkv [512,1536] f32 -> Wt [1536,512] bf16 ----------------
__global__ __launch_bounds__(256) void k_cvt_wt(const float* __restrict__ W,
                                                unsigned short* __restrict__ Wt) {
  __shared__ float tile[32][33];
  int kb = blockIdx.x;
  int nb = blockIdx.y;
  int t = threadIdx.x;
  int r = t >> 3, c4 = (t & 7) * 4;
  float4 v = *reinterpret_cast<const float4*>(W + (size_t)(kb * 32 + r) * 1536 + nb * 32 + c4);
  tile[r][c4 + 0] = v.x; tile[r][c4 + 1] = v.y; tile[r][c4 + 2] = v.z; tile[r][c4 + 3] = v.w;
  __syncthreads();
  int a = t >> 3, b4 = (t & 7) * 4;
  ushort4 o = { f2bf(tile[b4 + 0][a]), f2bf(tile[b4 + 1][a]),
                f2bf(tile[b4 + 2][a]), f2bf(tile[b4 + 3][a]) };
  *reinterpret_cast<ushort4*>(Wt + (size_t)(nb * 32 + a) * 512 + kb * 32 + b4) = o;
}

// ---------------- QKV = Xbf @ Wt^T -> [8192, 1536] bf16 ----------------
__global__ __launch_bounds__(256) void k_gemm_qkv(const unsigned short* __restrict__ Xbf,
                                                  const unsigned short* __restrict__ Wt,
                                                  unsigned short* __restrict__ QKV) {
  int m0 = blockIdx.x * 128;
  int n0 = blockIdx.y * 128;
  int w = threadIdx.x >> 6, lane = threadIdx.x & 63;
  int lr = lane & 15, g = lane >> 4;
  int wm = (w >> 1) * 64, wn = (w & 1) * 64;
  f32x4 acc[4][4];
  for (int i = 0; i < 4; ++i) for (int j = 0; j < 4; ++j) acc[i][j] = (f32x4){0.f, 0.f, 0.f, 0.f};
  const unsigned short* Ar[4]; const unsigned short* Br[4];
  for (int mt = 0; mt < 4; ++mt) Ar[mt] = Xbf + (size_t)(m0 + wm + mt * 16 + lr) * 512;
  for (int nt = 0; nt < 4; ++nt) Br[nt] = Wt  + (size_t)(n0 + wn + nt * 16 + lr) * 512;
#pragma unroll 2
  for (int ks = 0; ks < 16; ++ks) {
    int off = ks * 32 + g * 8;
    bf16x8 a[4], b[4];
    for (int mt = 0; mt < 4; ++mt)
      a[mt] = __builtin_bit_cast(bf16x8, *reinterpret_cast<const uint4*>(Ar[mt] + off));
    for (int nt = 0; nt < 4; ++nt)
      b[nt] = __builtin_bit_cast(bf16x8, *reinterpret_cast<const uint4*>(Br[nt] + off));
    for (int mt = 0; mt < 4; ++mt)
      for (int nt = 0; nt < 4; ++nt)
        acc[mt][nt] = __builtin_amdgcn_mfma_f32_16x16x32_bf16(a[mt], b[nt], acc[mt][nt], 0, 0, 0);
  }
  for (int mt = 0; mt < 4; ++mt)
    for (int nt = 0; nt < 4; ++nt)
      for (int r = 0; r < 4; ++r) {
        int m = m0 + wm + mt * 16 + g * 4 + r;
        int n = n0 + wn + nt * 16 + lr;
        QKV[(size_t)m * 1536 + n] = f2bf(acc[mt][nt][r]);
      }
}

// ---------------- Vt[b,h,d,l] <- QKV v-columns ----------------
__global__ __launch_bounds__(256) void k_vtrans(const unsigned short* __restrict__ QKV,
                                                unsigned short* __restrict__ Vt) {
  __shared__ unsigned short tile[64][72];
  int bh = blockIdx.x;
  int lt = blockIdx.y;
  int b = bh >> 3, h = bh & 7;
  int t = threadIdx.x;
  int i = t >> 2, d0 = (t & 3) * 16;
  const uint4* src = reinterpret_cast<const uint4*>(
      QKV + (size_t)(b * L_ + lt * 64 + i) * 1536 + 2 * D_MODEL + h * HD + d0);
  uint4 v0 = src[0], v1 = src[1];
  *reinterpret_cast<uint4*>(&tile[i][d0])     = v0;
  *reinterpret_cast<uint4*>(&tile[i][d0 + 8]) = v1;
  __syncthreads();
  int dd = t >> 2, c0 = (t & 3) * 16;
  unsigned short o[16];
  for (int j = 0; j < 16; ++j) o[j] = tile[c0 + j][dd];
  uint4* dst = reinterpret_cast<uint4*>(Vt + (size_t)(bh * HD + dd) * L_ + lt * 64 + c0);
  dst[0] = *reinterpret_cast<const uint4*>(&o[0]);
  dst[1] = *reinterpret_cast<const uint4*>(&o[8]);
}

// ---------------- sin/cos tables: SCF[l][d] f32, SBF bf16 ----------------
// d<32: sin(l*f_d); d>=32: cos(l*f_{d-32})
__global__ __launch_bounds__(256) void k_stab(float* __restrict__ SCF,
                                              unsigned short* __restrict__ SBF) {
  int tid = blockIdx.x * 256 + threadIdx.x;
  int l = tid >> 6, d = tid & 63;
  const float kInv = -9.210340371976184f / 31.0f;  // -ln(10000)/31
  float f = expf((float)(d & 31) * kInv);
  float ang = (float)l * f;
  float v = (d < 32) ? sinf(ang) : cosf(ang);
  SCF[tid] = v;
  SBF[tid] = f2bf(v);
}

// ---------------- Aq[bh][l][64] = rot(w_kr @ (q + rwb), pos=l) ----------------
__global__ __launch_bounds__(256) void k_aq(const unsigned short* __restrict__ QKV,
                                            const float* __restrict__ wkr,
                                            const float* __restrict__ rwb,
                                            const float* __restrict__ SCF,
                                            unsigned short* __restrict__ Aq) {
  __shared__ float wkrS[64][65];
  __shared__ float qS[64][65];
  __shared__ float zS[64][65];
  int blk = blockIdx.x;
  int bh = blk >> 4, lt = blk & 15;
  int b = bh >> 3, h = bh & 7;
  int t = threadIdx.x;
  for (int idx = t; idx < 4096; idx += 256) wkrS[idx >> 6][idx & 63] = wkr[idx];
  {
    int r = t >> 2, c0 = (t & 3) * 16;
    const unsigned short* qp = QKV + (size_t)(b * L_ + lt * 64 + r) * 1536 + h * HD;
    for (int jj = 0; jj < 16; ++jj) qS[r][c0 + jj] = bf2f(qp[c0 + jj]) + rwb[h * HD + c0 + jj];
  }
  __syncthreads();
  {
    int r = t >> 2, e0 = (t & 3) * 16;
    float acc[16];
    for (int ii = 0; ii < 16; ++ii) acc[ii] = 0.f;
    for (int d = 0; d < 64; ++d) {
      float qv = qS[r][d];
      for (int ii = 0; ii < 16; ++ii) acc[ii] += wkrS[e0 + ii][d] * qv;
    }
    for (int ii = 0; ii < 16; ++ii) zS[r][e0 + ii] = acc[ii];
  }
  __syncthreads();
  {
    int r = t >> 2, d0 = (t & 3) * 16;
    int pos = lt * 64 + r;
    const float* sc = SCF + (size_t)pos * 64;
    unsigned short* ap = Aq + ((size_t)bh * L_ + lt * 64 + r) * 64;
    for (int jj = 0; jj < 16; ++jj) {
      int d = d0 + jj;
      float a;
      if (d < 32) a = zS[r][d] * sc[d + 32] + zS[r][d + 32] * sc[d];
      else        a = zS[r][d] * sc[d]      - zS[r][d - 32] * sc[d - 32];
      ap[d] = f2bf(a);
    }
  }
}

// ---------------- fused relative attention (rank-64 factorized B-term) ----------------
__global__ __launch_bounds__(256, 3) void k_attn(const unsigned short* __restrict__ QKV,
                                                 const unsigned short* __restrict__ Vt,
                                                 const unsigned short* __restrict__ Sbf,
                                                 const unsigned short* __restrict__ Aq,
                                                 const int* __restrict__ mask,
                                                 const float* __restrict__ rrb,
                                                 float* __restrict__ out) {
  __shared__ unsigned short KtS[2][64][64];   // swizzled K tiles
  __shared__ unsigned short VtS[2][64][64];   // swizzled V^T tiles (dim-major)
  __shared__ int MtS[2][64];
  __shared__ unsigned short pS[4][16 * 72];

  int blk = blockIdx.x;
  int bh = blk >> 4, qt = blk & 15;
  int b = bh >> 3, h = bh & 7;
  int w = threadIdx.x >> 6, lane = threadIdx.x & 63;
  int lr = lane & 15, g = lane >> 4;
  int qw0 = qt * 64 + w * 16;
  int rsub = lane >> 3;            // 0..7: row within 8-row staging stripe
  int csub = (lane & 7) ^ rsub;    // inverse-swizzled source chunk
  int swz = lr & 7;

  // q fragments: qrr = q + r_r_bias (from QKV), qa (from Aq)
  bf16x8 qrr[2], qa[2];
  {
    const unsigned short* qrow = QKV + (size_t)(b * L_ + qw0 + lr) * 1536 + h * HD;
    const unsigned short* arow = Aq + ((size_t)bh * L_ + qw0 + lr) * HD;
#pragma unroll
    for (int ks = 0; ks < 2; ++ks) {
      uint4 raw = *reinterpret_cast<const uint4*>(qrow + ks * 32 + g * 8);
      unsigned short* rb = reinterpret_cast<unsigned short*>(&raw);
      unsigned short arr[8];
      for (int j = 0; j < 8; ++j) {
        int d = ks * 32 + g * 8 + j;
        arr[j] = f2bf(bf2f(rb[j]) + rrb[h * HD + d]);
      }
      qrr[ks] = __builtin_bit_cast(bf16x8, *reinterpret_cast<uint4*>(arr));
      qa[ks]  = __builtin_bit_cast(bf16x8, *reinterpret_cast<const uint4*>(arow + ks * 32 + g * 8));
    }
  }

  auto stage = [&](int nb, int k0n) {
#pragma unroll
    for (int j = 0; j < 2; ++j) {
      int row = w * 16 + j * 8;
      const unsigned short* gK = QKV + (size_t)(b * L_ + k0n + row + rsub) * 1536 +
                                 D_MODEL + h * HD + csub * 8;
      gld_lds16(gK, &KtS[nb][row][0]);
      const unsigned short* gV = Vt + (size_t)(bh * HD + row + rsub) * L_ + k0n + csub * 8;
      gld_lds16(gV, &VtS[nb][row][0]);
    }
    if (w == 0) gld_lds4(mask + b * L_ + k0n + lane, &MtS[nb][0]);
  };

  stage(0, 0);

  float m_r[4], l_r[4];
  f32x4 accO[4];
  for (int r = 0; r < 4; ++r) { m_r[r] = -INFINITY; l_r[r] = 0.f; }
  for (int nt = 0; nt < 4; ++nt) accO[nt] = (f32x4){0.f, 0.f, 0.f, 0.f};

  unsigned short* ps = pS[w];
  __syncthreads();

  for (int it = 0; it < 16; ++it) {
    int k0 = it << 6;
    int cur = it & 1;
    if (it < 15) stage(cur ^ 1, k0 + 64);

    // s-table fragments, direct from L2 (shared across all bh)
    bf16x8 sf[4][2];
#pragma unroll
    for (int t4 = 0; t4 < 4; ++t4)
#pragma unroll
      for (int ks = 0; ks < 2; ++ks)
        sf[t4][ks] = __builtin_bit_cast(bf16x8, *reinterpret_cast<const uint4*>(
            Sbf + (size_t)(k0 + t4 * 16 + lr) * HD + ks * 32 + g * 8));

    // scores: q.k (K=64 from LDS) + a.s (K=64 from regs)
    f32x4 ac[4];
#pragma unroll
    for (int t4 = 0; t4 < 4; ++t4) ac[t4] = (f32x4){0.f, 0.f, 0.f, 0.f};
#pragma unroll
    for (int t4 = 0; t4 < 4; ++t4)
#pragma unroll
      for (int ks = 0; ks < 2; ++ks) {
        const unsigned short* kp = &KtS[cur][t4 * 16 + lr][((((ks << 2) | g) ^ swz) << 3)];
        bf16x8 kfr = __builtin_bit_cast(bf16x8, *reinterpret_cast<const uint4*>(kp));
        ac[t4] = __builtin_amdgcn_mfma_f32_16x16x32_bf16(qrr[ks], kfr, ac[t4], 0, 0, 0);
      }
#pragma unroll
    for (int t4 = 0; t4 < 4; ++t4)
#pragma unroll
      for (int ks = 0; ks < 2; ++ks)
        ac[t4] = __builtin_amdgcn_mfma_f32_16x16x32_bf16(qa[ks], sf[t4][ks], ac[t4], 0, 0, 0);

    int mv[4];
#pragma unroll
    for (int t4 = 0; t4 < 4; ++t4) mv[t4] = MtS[cur][t4 * 16 + lr];

    // online softmax
    float p[4][4];
#pragma unroll
    for (int r = 0; r < 4; ++r) {
      float rm = -INFINITY;
#pragma unroll
      for (int t4 = 0; t4 < 4; ++t4) {
        float s = ac[t4][r] * SCALE;
        s = mv[t4] ? s : 1e-9f;
        p[t4][r] = s;
        rm = fmaxf(rm, s);
      }
      rm = fmaxf(rm, __shfl_xor(rm, 1, 16));
      rm = fmaxf(rm, __shfl_xor(rm, 2, 16));
      rm = fmaxf(rm, __shfl_xor(rm, 4, 16));
      rm = fmaxf(rm, __shfl_xor(rm, 8, 16));
      float mnew = fmaxf(m_r[r], rm);
      float alpha = __expf(m_r[r] - mnew);
      float rs = 0.f;
#pragma unroll
      for (int t4 = 0; t4 < 4; ++t4) {
        float e = __expf(p[t4][r] - mnew);
        p[t4][r] = e;
        rs += e;
      }
      rs += __shfl_xor(rs, 1, 16);
      rs += __shfl_xor(rs, 2, 16);
      rs += __shfl_xor(rs, 4, 16);
      rs += __shfl_xor(rs, 8, 16);
      l_r[r] = l_r[r] * alpha + rs;
      m_r[r] = mnew;
#pragma unroll
      for (int nt = 0; nt < 4; ++nt) accO[nt][r] *= alpha;
    }

    // P -> LDS (per-wave), A-fragments, PV
#pragma unroll
    for (int t4 = 0; t4 < 4; ++t4)
#pragma unroll
      for (int r = 0; r < 4; ++r)
        ps[(g * 4 + r) * 72 + t4 * 16 + lr] = f2bf(p[t4][r]);
    bf16x8 pa[2];
#pragma unroll
    for (int ks = 0; ks < 2; ++ks)
      pa[ks] = __builtin_bit_cast(bf16x8, *reinterpret_cast<const uint4*>(ps + lr * 72 + ks * 32 + g * 8));
#pragma unroll
    for (int nt = 0; nt < 4; ++nt)
#pragma unroll
      for (int ks = 0; ks < 2; ++ks) {
        const unsigned short* vp = &VtS[cur][nt * 16 + lr][((((ks << 2) | g) ^ swz) << 3)];
        bf16x8 vfr = __builtin_bit_cast(bf16x8, *reinterpret_cast<const uint4*>(vp));
        accO[nt] = __builtin_amdgcn_mfma_f32_16x16x32_bf16(pa[ks], vfr, accO[nt], 0, 0, 0);
      }
    __syncthreads();
  }

#pragma unroll
  for (int nt = 0; nt < 4; ++nt)
#pragma unroll
    for (int r = 0; r < 4; ++r) {
      int q = qw0 + g * 4 + r;
      out[(size_t)(b * L_ + q) * D_MODEL + h * HD + nt * 16 + lr] = accO[nt][r] / l_r[r];
    }
}

extern "C" void kernel_launch(void* const* d_in, const int* in_sizes, int n_in,
                              void* d_out, int out_size, void* d_ws, size_t ws_size,
                              hipStream_t stream) {
  const float* x    = (const float*)d_in[0];
  const int*   mask = (const int*)d_in[1];
  const float* Wqkv = (const float*)d_in[2];
  const float* rrb  = (const float*)d_in[3];
  const float* rwb  = (const float*)d_in[4];
  const float* wkr  = (const float*)d_in[5];
  float* out = (float*)d_out;

  char* ws = (char*)d_ws;
  size_t off = 0;
  unsigned short* XBF = (unsigned short*)(ws + off); off += (size_t)8192 * 512 * 2;      // 8 MB
  unsigned short* WT  = (unsigned short*)(ws + off); off += (size_t)1536 * 512 * 2;      // 1.5 MB
  unsigned short* QKV = (unsigned short*)(ws + off); off += (size_t)8192 * 1536 * 2;     // 24 MB
  unsigned short* VT  = (unsigned short*)(ws + off); off += (size_t)64 * 64 * 1024 * 2;  // 8 MB
  float*          SCF = (float*)(ws + off);          off += (size_t)1024 * 64 * 4;       // 256 KB
  unsigned short* SBF = (unsigned short*)(ws + off); off += (size_t)1024 * 64 * 2;       // 128 KB
  unsigned short* AQ  = XBF;  // reuse: XBF dead after k_gemm_qkv; k_aq runs after it

  hipLaunchKernelGGL(k_cvt_x,    dim3(2048),   dim3(256), 0, stream, x, XBF);
  hipLaunchKernelGGL(k_cvt_wt,   dim3(16, 48), dim3(256), 0, stream, Wqkv, WT);
  hipLaunchKernelGGL(k_stab,     dim3(256),    dim3(256), 0, stream, SCF, SBF);
  hipLaunchKernelGGL(k_gemm_qkv, dim3(64, 12), dim3(256), 0, stream, XBF, WT, QKV);
  hipLaunchKernelGGL(k_vtrans,   dim3(64, 16), dim3(256), 0, stream, QKV, VT);
  hipLaunchKernelGGL(k_aq,       dim3(1024),   dim3(256), 0, stream, QKV, wkr, rwb, SCF, AQ);
  hipLaunchKernelGGL(k_attn,     dim3(1024),   dim3(256), 0, stream, QKV, VT, SBF, AQ, mask, rrb, out);
}

// Round 3
// 128.136 us; speedup vs baseline: 2.2514x; 1.5878x over previous
//
#include <hip/hip_runtime.h>
#include <hip/hip_bf16.h>
#include <stdint.h>

typedef __bf16 bf16x8 __attribute__((ext_vector_type(8)));
typedef float  f32x4  __attribute__((ext_vector_type(4)));

#define D_MODEL 512
#define N_HEAD  8
#define HD      64
#define L_      1024
#define SCALE   0.125f

__device__ __forceinline__ unsigned short f2bf(float f) {
  unsigned int u = __builtin_bit_cast(unsigned int, f);
  u += 0x7FFFu + ((u >> 16) & 1u);
  return (unsigned short)(u >> 16);
}
__device__ __forceinline__ float bf2f(unsigned short h) {
  unsigned int u = ((unsigned int)h) << 16;
  return __builtin_bit_cast(float, u);
}

__device__ __forceinline__ void gld_lds16(const void* g, void* l) {
  __builtin_amdgcn_global_load_lds(
      (const __attribute__((address_space(1))) void*)g,
      (__attribute__((address_space(3))) void*)l, 16, 0, 0);
}
__device__ __forceinline__ void gld_lds4(const void* g, void* l) {
  __builtin_amdgcn_global_load_lds(
      (const __attribute__((address_space(1))) void*)g,
      (__attribute__((address_space(3))) void*)l, 4, 0, 0);
}

// ---------------- x (f32) -> bf16 ----------------
__global__ __launch_bounds__(256) void k_cvt_x(const float* __restrict__ x,
                                               unsigned short* __restrict__ xbf) {
  int t = blockIdx.x * 256 + threadIdx.x;
  const float4* p = reinterpret_cast<const float4*>(x) + (size_t)t * 2;
  float4 a = p[0], b = p[1];
  ushort4 o0 = { f2bf(a.x), f2bf(a.y), f2bf(a.z), f2bf(a.w) };
  ushort4 o1 = { f2bf(b.x), f2bf(b.y), f2bf(b.z), f2bf(b.w) };
  ushort4* q = reinterpret_cast<ushort4*>(xbf) + (size_t)t * 2;
  q[0] = o0; q[1] = o1;
}

// ---------------- W_qkv [512,1536] f32 -> Wt [1536,512] bf16 ----------------
__global__ __launch_bounds__(256) void k_cvt_wt(const float* __restrict__ W,
                                                unsigned short* __restrict__ Wt) {
  __shared__ float tile[32][33];
  int kb = blockIdx.x;
  int nb = blockIdx.y;
  int t = threadIdx.x;
  int r = t >> 3, c4 = (t & 7) * 4;
  float4 v = *reinterpret_cast<const float4*>(W + (size_t)(kb * 32 + r) * 1536 + nb * 32 + c4);
  tile[r][c4 + 0] = v.x; tile[r][c4 + 1] = v.y; tile[r][c4 + 2] = v.z; tile[r][c4 + 3] = v.w;
  __syncthreads();
  int a = t >> 3, b4 = (t & 7) * 4;
  ushort4 o = { f2bf(tile[b4 + 0][a]), f2bf(tile[b4 + 1][a]),
                f2bf(tile[b4 + 2][a]), f2bf(tile[b4 + 3][a]) };
  *reinterpret_cast<ushort4*>(Wt + (size_t)(nb * 32 + a) * 512 + kb * 32 + b4) = o;
}

// ---------------- QKV = Xbf @ Wt^T -> [8192, 1536] bf16 (LDS-staged, m97-style) ----------------
__global__ __launch_bounds__(256, 3) void k_gemm_qkv(const unsigned short* __restrict__ Xbf,
                                                     const unsigned short* __restrict__ Wt,
                                                     unsigned short* __restrict__ QKV) {
  __shared__ unsigned short As[2][128][32];
  __shared__ unsigned short Bs[2][128][32];
  int m0 = blockIdx.x * 128;
  int n0 = blockIdx.y * 128;
  int w = threadIdx.x >> 6, lane = threadIdx.x & 63;
  int lr = lane & 15, g = lane >> 4;
  int wm = (w >> 1) * 64, wn = (w & 1) * 64;
  int srow = lane >> 2, schk = (lane & 3) * 8;

  auto stage = [&](int buf, int k0) {
#pragma unroll
    for (int j = 0; j < 2; ++j) {
      int row = w * 32 + j * 16 + srow;
      gld_lds16(Xbf + (size_t)(m0 + row) * 512 + k0 + schk, &As[buf][w * 32 + j * 16][0]);
      gld_lds16(Wt  + (size_t)(n0 + row) * 512 + k0 + schk, &Bs[buf][w * 32 + j * 16][0]);
    }
  };

  f32x4 acc[4][4];
  for (int i = 0; i < 4; ++i) for (int j = 0; j < 4; ++j) acc[i][j] = (f32x4){0.f, 0.f, 0.f, 0.f};

  stage(0, 0);
  __syncthreads();

  for (int it = 0; it < 16; ++it) {
    int cur = it & 1;
    if (it < 15) stage(cur ^ 1, (it + 1) * 32);
    bf16x8 a[4], b[4];
#pragma unroll
    for (int mt = 0; mt < 4; ++mt)
      a[mt] = __builtin_bit_cast(bf16x8, *reinterpret_cast<const uint4*>(&As[cur][wm + mt * 16 + lr][g * 8]));
#pragma unroll
    for (int nt = 0; nt < 4; ++nt)
      b[nt] = __builtin_bit_cast(bf16x8, *reinterpret_cast<const uint4*>(&Bs[cur][wn + nt * 16 + lr][g * 8]));
#pragma unroll
    for (int mt = 0; mt < 4; ++mt)
#pragma unroll
      for (int nt = 0; nt < 4; ++nt)
        acc[mt][nt] = __builtin_amdgcn_mfma_f32_16x16x32_bf16(a[mt], b[nt], acc[mt][nt], 0, 0, 0);
    __syncthreads();
  }

#pragma unroll
  for (int mt = 0; mt < 4; ++mt)
#pragma unroll
    for (int nt = 0; nt < 4; ++nt)
#pragma unroll
      for (int r = 0; r < 4; ++r) {
        int m = m0 + wm + mt * 16 + g * 4 + r;
        int n = n0 + wn + nt * 16 + lr;
        QKV[(size_t)m * 1536 + n] = f2bf(acc[mt][nt][r]);
      }
}

// ---------------- Vt[b,h,d,l] <- QKV v-columns ----------------
__global__ __launch_bounds__(256) void k_vtrans(const unsigned short* __restrict__ QKV,
                                                unsigned short* __restrict__ Vt) {
  __shared__ unsigned short tile[64][72];
  int bh = blockIdx.x;
  int lt = blockIdx.y;
  int b = bh >> 3, h = bh & 7;
  int t = threadIdx.x;
  int i = t >> 2, d0 = (t & 3) * 16;
  const uint4* src = reinterpret_cast<const uint4*>(
      QKV + (size_t)(b * L_ + lt * 64 + i) * 1536 + 2 * D_MODEL + h * HD + d0);
  uint4 v0 = src[0], v1 = src[1];
  *reinterpret_cast<uint4*>(&tile[i][d0])     = v0;
  *reinterpret_cast<uint4*>(&tile[i][d0 + 8]) = v1;
  __syncthreads();
  int dd = t >> 2, c0 = (t & 3) * 16;
  unsigned short o[16];
  for (int j = 0; j < 16; ++j) o[j] = tile[c0 + j][dd];
  uint4* dst = reinterpret_cast<uint4*>(Vt + (size_t)(bh * HD + dd) * L_ + lt * 64 + c0);
  dst[0] = *reinterpret_cast<const uint4*>(&o[0]);
  dst[1] = *reinterpret_cast<const uint4*>(&o[8]);
}

// ---------------- sin/cos tables: SCF[l][d] f32, SBF bf16 ----------------
__global__ __launch_bounds__(256) void k_stab(float* __restrict__ SCF,
                                              unsigned short* __restrict__ SBF) {
  int tid = blockIdx.x * 256 + threadIdx.x;
  int l = tid >> 6, d = tid & 63;
  const float kInv = -9.210340371976184f / 31.0f;  // -ln(10000)/31
  float f = expf((float)(d & 31) * kInv);
  float ang = (float)l * f;
  float v = (d < 32) ? sinf(ang) : cosf(ang);
  SCF[tid] = v;
  SBF[tid] = f2bf(v);
}

// ---------------- Aq[bh][l][64] = rot(w_kr @ (q + rwb), pos=l) ----------------
__global__ __launch_bounds__(256) void k_aq(const unsigned short* __restrict__ QKV,
                                            const float* __restrict__ wkr,
                                            const float* __restrict__ rwb,
                                            const float* __restrict__ SCF,
                                            unsigned short* __restrict__ Aq) {
  __shared__ float wkrS[64][65];
  __shared__ float qS[64][65];
  __shared__ float zS[64][65];
  int blk = blockIdx.x;
  int bh = blk >> 4, lt = blk & 15;
  int b = bh >> 3, h = bh & 7;
  int t = threadIdx.x;
  for (int idx = t; idx < 4096; idx += 256) wkrS[idx >> 6][idx & 63] = wkr[idx];
  {
    int r = t >> 2, c0 = (t & 3) * 16;
    const unsigned short* qp = QKV + (size_t)(b * L_ + lt * 64 + r) * 1536 + h * HD;
    for (int jj = 0; jj < 16; ++jj) qS[r][c0 + jj] = bf2f(qp[c0 + jj]) + rwb[h * HD + c0 + jj];
  }
  __syncthreads();
  {
    int r = t >> 2, e0 = (t & 3) * 16;
    float acc[16];
    for (int ii = 0; ii < 16; ++ii) acc[ii] = 0.f;
    for (int d = 0; d < 64; ++d) {
      float qv = qS[r][d];
      for (int ii = 0; ii < 16; ++ii) acc[ii] += wkrS[e0 + ii][d] * qv;
    }
    for (int ii = 0; ii < 16; ++ii) zS[r][e0 + ii] = acc[ii];
  }
  __syncthreads();
  {
    int r = t >> 2, d0 = (t & 3) * 16;
    int pos = lt * 64 + r;
    const float* sc = SCF + (size_t)pos * 64;
    unsigned short* ap = Aq + ((size_t)bh * L_ + lt * 64 + r) * 64;
    for (int jj = 0; jj < 16; ++jj) {
      int d = d0 + jj;
      float a;
      if (d < 32) a = zS[r][d] * sc[d + 32] + zS[r][d + 32] * sc[d];
      else        a = zS[r][d] * sc[d]      - zS[r][d - 32] * sc[d - 32];
      ap[d] = f2bf(a);
    }
  }
}

// ---------------- fused relative attention: QBLK=128, constant-max softmax ----------------
__global__ __launch_bounds__(256, 3) void k_attn(const unsigned short* __restrict__ QKV,
                                                 const unsigned short* __restrict__ Vt,
                                                 const unsigned short* __restrict__ Sbf,
                                                 const unsigned short* __restrict__ Aq,
                                                 const int* __restrict__ mask,
                                                 const float* __restrict__ rrb,
                                                 float* __restrict__ out) {
  __shared__ unsigned short KtS[2][64][64];   // swizzled K tiles (row stride 128B needs XOR)
  __shared__ unsigned short VtS[2][64][64];   // swizzled V^T tiles
  __shared__ int MtS[2][64];
  __shared__ unsigned short pS[4][32 * 72];

  int blk = blockIdx.x;
  int bh = blk >> 3, qt = blk & 7;
  int b = bh >> 3, h = bh & 7;
  int w = threadIdx.x >> 6, lane = threadIdx.x & 63;
  int lr = lane & 15, g = lane >> 4;
  int qw0 = qt * 128 + w * 32;               // 32 q-rows per wave (2 subtiles of 16)
  int rsub = lane >> 3;
  int csub = (lane & 7) ^ rsub;
  int swz = lr & 7;

  // q fragments (scale 0.125 folded in; exact bf16 exponent shift)
  bf16x8 qrr[2][2], qa[2][2];
#pragma unroll
  for (int mt = 0; mt < 2; ++mt) {
    const unsigned short* qrow = QKV + (size_t)(b * L_ + qw0 + mt * 16 + lr) * 1536 + h * HD;
    const unsigned short* arow = Aq + ((size_t)bh * L_ + qw0 + mt * 16 + lr) * HD;
#pragma unroll
    for (int ks = 0; ks < 2; ++ks) {
      uint4 raw = *reinterpret_cast<const uint4*>(qrow + ks * 32 + g * 8);
      uint4 araw = *reinterpret_cast<const uint4*>(arow + ks * 32 + g * 8);
      unsigned short* rb = reinterpret_cast<unsigned short*>(&raw);
      unsigned short* ab = reinterpret_cast<unsigned short*>(&araw);
      unsigned short arr[8], aarr[8];
      for (int j = 0; j < 8; ++j) {
        int d = ks * 32 + g * 8 + j;
        arr[j]  = f2bf((bf2f(rb[j]) + rrb[h * HD + d]) * SCALE);
        aarr[j] = f2bf(bf2f(ab[j]) * SCALE);
      }
      qrr[mt][ks] = __builtin_bit_cast(bf16x8, *reinterpret_cast<uint4*>(arr));
      qa[mt][ks]  = __builtin_bit_cast(bf16x8, *reinterpret_cast<uint4*>(aarr));
    }
  }

  auto stage = [&](int nb, int k0n) {
#pragma unroll
    for (int j = 0; j < 2; ++j) {
      int row = w * 16 + j * 8;
      const unsigned short* gK = QKV + (size_t)(b * L_ + k0n + row + rsub) * 1536 +
                                 D_MODEL + h * HD + csub * 8;
      gld_lds16(gK, &KtS[nb][row][0]);
      const unsigned short* gV = Vt + (size_t)(bh * HD + row + rsub) * L_ + k0n + csub * 8;
      gld_lds16(gV, &VtS[nb][row][0]);
    }
    if (w == 0) gld_lds4(mask + b * L_ + k0n + lane, &MtS[nb][0]);
  };

  stage(0, 0);

  float lsum[2][4];
  f32x4 accO[2][4];
#pragma unroll
  for (int mt = 0; mt < 2; ++mt)
#pragma unroll
    for (int r = 0; r < 4; ++r) lsum[mt][r] = 0.f;
#pragma unroll
  for (int mt = 0; mt < 2; ++mt)
#pragma unroll
    for (int nt = 0; nt < 4; ++nt) accO[mt][nt] = (f32x4){0.f, 0.f, 0.f, 0.f};

  unsigned short* ps = pS[w];
  __syncthreads();

  for (int it = 0; it < 16; ++it) {
    int k0 = it << 6;
    int cur = it & 1;
    if (it < 15) stage(cur ^ 1, k0 + 64);

    // scores: (q+rrb)*0.125 . k  +  a*0.125 . s   (pre-scaled)
    f32x4 ac[2][4];
#pragma unroll
    for (int mt = 0; mt < 2; ++mt)
#pragma unroll
      for (int t4 = 0; t4 < 4; ++t4) ac[mt][t4] = (f32x4){0.f, 0.f, 0.f, 0.f};
#pragma unroll
    for (int t4 = 0; t4 < 4; ++t4) {
#pragma unroll
      for (int ks = 0; ks < 2; ++ks) {
        const unsigned short* kp = &KtS[cur][t4 * 16 + lr][((((ks << 2) | g) ^ swz) << 3)];
        bf16x8 kfr = __builtin_bit_cast(bf16x8, *reinterpret_cast<const uint4*>(kp));
        ac[0][t4] = __builtin_amdgcn_mfma_f32_16x16x32_bf16(qrr[0][ks], kfr, ac[0][t4], 0, 0, 0);
        ac[1][t4] = __builtin_amdgcn_mfma_f32_16x16x32_bf16(qrr[1][ks], kfr, ac[1][t4], 0, 0, 0);
      }
#pragma unroll
      for (int ks = 0; ks < 2; ++ks) {
        bf16x8 sfr = __builtin_bit_cast(bf16x8, *reinterpret_cast<const uint4*>(
            Sbf + (size_t)(k0 + t4 * 16 + lr) * HD + ks * 32 + g * 8));
        ac[0][t4] = __builtin_amdgcn_mfma_f32_16x16x32_bf16(qa[0][ks], sfr, ac[0][t4], 0, 0, 0);
        ac[1][t4] = __builtin_amdgcn_mfma_f32_16x16x32_bf16(qa[1][ks], sfr, ac[1][t4], 0, 0, 0);
      }
    }

    int mv[4];
#pragma unroll
    for (int t4 = 0; t4 < 4; ++t4) mv[t4] = MtS[cur][t4 * 16 + lr];

    // constant-max softmax: p = exp(s - 8), deferred denominator
#pragma unroll
    for (int mt = 0; mt < 2; ++mt)
#pragma unroll
      for (int t4 = 0; t4 < 4; ++t4)
#pragma unroll
        for (int r = 0; r < 4; ++r) {
          float s = mv[t4] ? ac[mt][t4][r] : 1e-9f;
          float e = __expf(s - 8.f);
          lsum[mt][r] += e;
          ps[(mt * 16 + g * 4 + r) * 72 + t4 * 16 + lr] = f2bf(e);
        }

    // P fragments + PV
    bf16x8 pa[2][2];
#pragma unroll
    for (int mt = 0; mt < 2; ++mt)
#pragma unroll
      for (int ks = 0; ks < 2; ++ks)
        pa[mt][ks] = __builtin_bit_cast(bf16x8, *reinterpret_cast<const uint4*>(
            ps + (mt * 16 + lr) * 72 + ks * 32 + g * 8));
#pragma unroll
    for (int nt = 0; nt < 4; ++nt)
#pragma unroll
      for (int ks = 0; ks < 2; ++ks) {
        const unsigned short* vp = &VtS[cur][nt * 16 + lr][((((ks << 2) | g) ^ swz) << 3)];
        bf16x8 vfr = __builtin_bit_cast(bf16x8, *reinterpret_cast<const uint4*>(vp));
        accO[0][nt] = __builtin_amdgcn_mfma_f32_16x16x32_bf16(pa[0][ks], vfr, accO[0][nt], 0, 0, 0);
        accO[1][nt] = __builtin_amdgcn_mfma_f32_16x16x32_bf16(pa[1][ks], vfr, accO[1][nt], 0, 0, 0);
      }
    __syncthreads();
  }

  // one-time denominator reduce across the 16 k-lanes
#pragma unroll
  for (int mt = 0; mt < 2; ++mt)
#pragma unroll
    for (int r = 0; r < 4; ++r) {
      float s = lsum[mt][r];
      s += __shfl_xor(s, 1, 16);
      s += __shfl_xor(s, 2, 16);
      s += __shfl_xor(s, 4, 16);
      s += __shfl_xor(s, 8, 16);
      lsum[mt][r] = s;
    }

#pragma unroll
  for (int mt = 0; mt < 2; ++mt)
#pragma unroll
    for (int nt = 0; nt < 4; ++nt)
#pragma unroll
      for (int r = 0; r < 4; ++r) {
        int q = qw0 + mt * 16 + g * 4 + r;
        out[(size_t)(b * L_ + q) * D_MODEL + h * HD + nt * 16 + lr] = accO[mt][nt][r] / lsum[mt][r];
      }
}

extern "C" void kernel_launch(void* const* d_in, const int* in_sizes, int n_in,
                              void* d_out, int out_size, void* d_ws, size_t ws_size,
                              hipStream_t stream) {
  const float* x    = (const float*)d_in[0];
  const int*   mask = (const int*)d_in[1];
  const float* Wqkv = (const float*)d_in[2];
  const float* rrb  = (const float*)d_in[3];
  const float* rwb  = (const float*)d_in[4];
  const float* wkr  = (const float*)d_in[5];
  float* out = (float*)d_out;

  char* ws = (char*)d_ws;
  size_t off = 0;
  unsigned short* XBF = (unsigned short*)(ws + off); off += (size_t)8192 * 512 * 2;
  unsigned short* WT  = (unsigned short*)(ws + off); off += (size_t)1536 * 512 * 2;
  unsigned short* QKV = (unsigned short*)(ws + off); off += (size_t)8192 * 1536 * 2;
  unsigned short* VT  = (unsigned short*)(ws + off); off += (size_t)64 * 64 * 1024 * 2;
  float*          SCF = (float*)(ws + off);          off += (size_t)1024 * 64 * 4;
  unsigned short* SBF = (unsigned short*)(ws + off); off += (size_t)1024 * 64 * 2;
  unsigned short* AQ  = XBF;  // XBF dead after k_gemm_qkv

  hipLaunchKernelGGL(k_cvt_x,    dim3(2048),   dim3(256), 0, stream, x, XBF);
  hipLaunchKernelGGL(k_cvt_wt,   dim3(16, 48), dim3(256), 0, stream, Wqkv, WT);
  hipLaunchKernelGGL(k_stab,     dim3(256),    dim3(256), 0, stream, SCF, SBF);
  hipLaunchKernelGGL(k_gemm_qkv, dim3(64, 12), dim3(256), 0, stream, XBF, WT, QKV);
  hipLaunchKernelGGL(k_vtrans,   dim3(64, 16), dim3(256), 0, stream, QKV, VT);
  hipLaunchKernelGGL(k_aq,       dim3(1024),   dim3(256), 0, stream, QKV, wkr, rwb, SCF, AQ);
  hipLaunchKernelGGL(k_attn,     dim3(512),    dim3(256), 0, stream, QKV, VT, SBF, AQ, mask, rrb, out);
}